// Round 5
// baseline (194.703 us; speedup 1.0000x reference)
//
#include <hip/hip_runtime.h>
#include <hip/hip_bf16.h>
#include <hip/hip_cooperative_groups.h>
namespace cg = cooperative_groups;

// Problem constants
#define VOCAB 50000
#define ED    300
#define NT    16
#define BB    64
#define SS    512

#define LOG2E 1.4426950408889634f
#define LN2   0.6931471805599453f
#define WSTR  308   // padded W-transpose stride: bank (20t+4c)%32 -> 2-way, free
#define GRID  256
#define BLK   1024

// ---------------------------------------------------------------------------
// DPP helpers (controls HW-verified rounds 1-4). old = src (involutions, all
// lanes active -> old never observed).
//   0xB1 quad_perm lane^1, 0x4E lane^2, 0x1B lane^3,
//   0x141 row_half_mirror lane^7, 0x140 row_mirror lane^15.
// ---------------------------------------------------------------------------
template <int CTRL>
__device__ __forceinline__ float dppmov(float x) {
  int xi = __float_as_int(x);
  return __int_as_float(
      __builtin_amdgcn_update_dpp(xi, xi, CTRL, 0xF, 0xF, false));
}

// ---------------------------------------------------------------------------
// One CRF forward step, fused DPP matvec (HW-verified rounds 3-4).
//   gn_j = (sum_k alpha_{j^k} * E[k]_j) * pe_j,  E[k]_j = exp(trans[j^k, j])
// ---------------------------------------------------------------------------
__device__ __forceinline__ float crf_step(float g, float pe, const float E[16]) {
  float gn, h, m, c, a1, a2, a3;
  asm("s_nop 1\n\t"
      "v_mov_b32_dpp %[h], %[g] row_half_mirror row_mask:0xf bank_mask:0xf\n\t"
      "v_mov_b32_dpp %[m], %[g] row_mirror row_mask:0xf bank_mask:0xf\n\t"
      "v_mul_f32 %[gn], %[g], %[e0]\n\t"
      "v_fmac_f32_dpp %[gn], %[g], %[e1] quad_perm:[1,0,3,2] row_mask:0xf bank_mask:0xf\n\t"
      "v_fmac_f32_dpp %[gn], %[g], %[e2] quad_perm:[2,3,0,1] row_mask:0xf bank_mask:0xf\n\t"
      "v_fmac_f32_dpp %[gn], %[g], %[e3] quad_perm:[3,2,1,0] row_mask:0xf bank_mask:0xf\n\t"
      "v_mov_b32_dpp %[c], %[m] row_half_mirror row_mask:0xf bank_mask:0xf\n\t"
      "v_mul_f32 %[a1], %[h], %[e7]\n\t"
      "v_fmac_f32_dpp %[a1], %[h], %[e6] quad_perm:[1,0,3,2] row_mask:0xf bank_mask:0xf\n\t"
      "v_fmac_f32_dpp %[a1], %[h], %[e5] quad_perm:[2,3,0,1] row_mask:0xf bank_mask:0xf\n\t"
      "v_fmac_f32_dpp %[a1], %[h], %[e4] quad_perm:[3,2,1,0] row_mask:0xf bank_mask:0xf\n\t"
      "v_mul_f32 %[a2], %[m], %[e15]\n\t"
      "v_fmac_f32_dpp %[a2], %[m], %[e14] quad_perm:[1,0,3,2] row_mask:0xf bank_mask:0xf\n\t"
      "v_fmac_f32_dpp %[a2], %[m], %[e13] quad_perm:[2,3,0,1] row_mask:0xf bank_mask:0xf\n\t"
      "v_fmac_f32_dpp %[a2], %[m], %[e12] quad_perm:[3,2,1,0] row_mask:0xf bank_mask:0xf\n\t"
      "v_mul_f32 %[a3], %[c], %[e8]\n\t"
      "v_fmac_f32_dpp %[a3], %[c], %[e9] quad_perm:[1,0,3,2] row_mask:0xf bank_mask:0xf\n\t"
      "v_fmac_f32_dpp %[a3], %[c], %[e10] quad_perm:[2,3,0,1] row_mask:0xf bank_mask:0xf\n\t"
      "v_fmac_f32_dpp %[a3], %[c], %[e11] quad_perm:[3,2,1,0] row_mask:0xf bank_mask:0xf\n\t"
      "v_add_f32 %[gn], %[gn], %[a1]\n\t"
      "v_add_f32 %[a2], %[a2], %[a3]\n\t"
      "v_add_f32 %[gn], %[gn], %[a2]\n\t"
      "v_mul_f32 %[gn], %[gn], %[pe]"
      : [gn] "=&v"(gn), [h] "=&v"(h), [m] "=&v"(m), [c] "=&v"(c),
        [a1] "=&v"(a1), [a2] "=&v"(a2), [a3] "=&v"(a3)
      : [g] "v"(g), [pe] "v"(pe),
        [e0] "v"(E[0]), [e1] "v"(E[1]), [e2] "v"(E[2]), [e3] "v"(E[3]),
        [e4] "v"(E[4]), [e5] "v"(E[5]), [e6] "v"(E[6]), [e7] "v"(E[7]),
        [e8] "v"(E[8]), [e9] "v"(E[9]), [e10] "v"(E[10]), [e11] "v"(E[11]),
        [e12] "v"(E[12]), [e13] "v"(E[13]), [e14] "v"(E[14]), [e15] "v"(E[15]));
  return gn;
}

// ---------------------------------------------------------------------------
// Fused cooperative kernel.
// Phase 1 (all 256 blocks, 16 waves): probs rows [blk*128, blk*128+128).
//   Lane layout r=lane>>4 (row pair), t=lane&15 (tag). 2 rows per lane
//   interleaved (shared W ds_read), depth-4x2 rolling e-prefetch.
// grid.sync() (device-scope fence).
// Phase 2 (blocks 0..63): stage batch probs->LDS with all 1024 threads, then
//   wave 0 runs lens + phase A + the serial DPP scan (round-4-verified).
// LDS: union of W-transpose (4928 f) and lps/tgs/trs (8976 f = 35.9 KB).
// ---------------------------------------------------------------------------
__global__ __launch_bounds__(BLK, 4) void fused_kernel(
    const int* __restrict__ text, const int* __restrict__ tags,
    const float* __restrict__ emb, const float* __restrict__ W,
    const float* __restrict__ bias, const float* __restrict__ trans,
    float* __restrict__ out_probs, float* __restrict__ out_lens,
    float* __restrict__ out_ll) {
  __shared__ float smem[8976];
  float* wt = smem;                       // phase 1: 16*308 floats
  float* lps = smem;                      // phase 2: (512+1)*16 floats
  int* tgs = (int*)(smem + 8208);         // 512 ints (16B-aligned)
  float* trs = smem + 8208 + 512;         // 256 floats

  const int tid = threadIdx.x;
  const int wave = tid >> 6, lane = tid & 63;
  const int r = lane >> 4, t = lane & 15;

  // ---- phase 1: stage W transposed ----
  for (int e = tid; e < ED * NT; e += BLK) {
    int d = e >> 4, tt = e & 15;
    wt[tt * WSTR + d] = W[e];
  }

  const int row0 = blockIdx.x * 128 + wave * 8 + r;  // and row0+4
  const int tok0 = text[row0];
  const int tok1 = text[row0 + 4];
  const float4* er0 = (const float4*)(emb + (size_t)tok0 * ED);
  const float4* er1 = (const float4*)(emb + (size_t)tok1 * ED);
  float acc0 = bias[t];
  float acc1 = acc0;

  float4 A0[4], A1[4];
#pragma unroll
  for (int i = 0; i < 4; ++i) { A0[i] = er0[i]; A1[i] = er1[i]; }

  __syncthreads();  // wt ready

  const float4* w4 = (const float4*)(wt + t * WSTR);
#pragma unroll
  for (int c = 0; c < 75; ++c) {
    float4 e0 = A0[c & 3], e1 = A1[c & 3];
    if (c < 71) { A0[c & 3] = er0[c + 4]; A1[c & 3] = er1[c + 4]; }
    float4 w = w4[c];
    acc0 = fmaf(e0.x, w.x, acc0); acc0 = fmaf(e0.y, w.y, acc0);
    acc0 = fmaf(e0.z, w.z, acc0); acc0 = fmaf(e0.w, w.w, acc0);
    acc1 = fmaf(e1.x, w.x, acc1); acc1 = fmaf(e1.y, w.y, acc1);
    acc1 = fmaf(e1.z, w.z, acc1); acc1 = fmaf(e1.w, w.w, acc1);
  }
  out_probs[(size_t)row0 * NT + t] = acc0;
  out_probs[(size_t)(row0 + 4) * NT + t] = acc1;

  cg::this_grid().sync();  // all probs visible device-wide

  const int b = blockIdx.x;
  if (b >= BB) return;  // uniform per block

  // ---- phase 2 staging (all 1024 threads) ----
  {
    const float4* p4 = (const float4*)(out_probs + (size_t)b * SS * NT);
    float4* l4 = (float4*)lps;
#pragma unroll
    for (int i = 0; i < 2; ++i) {
      float4 v = p4[tid + BLK * i];
      v.x *= LOG2E; v.y *= LOG2E; v.z *= LOG2E; v.w *= LOG2E;
      l4[tid + BLK * i] = v;
    }
    if (tid < 128) ((int4*)tgs)[tid] = ((const int4*)(tags + b * SS))[tid];
    if (tid < 256) trs[tid] = trans[tid];
  }
  __syncthreads();
  if (wave != 0) return;  // wave 0 carries the scan; no more barriers

  // ---- lens ----
  const int* tx = text + b * SS;
  int cnt = 0;
#pragma unroll
  for (int k = 0; k < 8; ++k) cnt += (tx[lane + 64 * k] != 0) ? 1 : 0;
  for (int off = 32; off > 0; off >>= 1) cnt += __shfl_xor(cnt, off, 64);
  const int len = cnt;
  if (lane == 0) out_lens[b] = (float)len;

  // ---- phase A: unary + binary scores ----
  float su = 0.f, sb = 0.f;
#pragma unroll
  for (int it = 0; it < 8; ++it) {
    const int s = lane + 64 * it;
    if (s < len) {
      int t1 = tgs[s];
      su += lps[s * NT + t1];
      if (s >= 1) sb += trs[tgs[s - 1] * 16 + t1];
    }
  }
  float sc = fmaf(su, LN2, sb);
  for (int off = 32; off > 0; off >>= 1) sc += __shfl_xor(sc, off, 64);

  // ---- E[k] = exp(trans[j^k, j]), j = lane&15 ----
  const int j = lane & 15;
  float E[16];
#pragma unroll
  for (int k = 0; k < 16; ++k) E[k] = __expf(trs[((j ^ k) << 4) + j]);

  // ---- scan: s = 1 .. len-1 (steps s>=len are exact no-ops; skip them) ----
  float g = exp2f(lps[j]);
  float K2 = 0.f;

  const int T = (len > 0) ? len - 1 : 0;
  const int nfull = T >> 4;
  const int rem = T & 15;

  float raw[16];
#pragma unroll
  for (int c = 0; c < 16; ++c) raw[c] = lps[(1 + c) * NT + j];

  int s0 = 1;
  for (int blk = 0; blk < nfull; ++blk) {
#pragma unroll
    for (int c = 0; c < 16; ++c) {
      float pe = exp2f(raw[c]);
      raw[c] = lps[(s0 + 16 + c) * NT + j];  // rows <= 512 (pad row)
      g = crf_step(g, pe, E);
    }
    // renorm every 16 steps (growth <= 2^90 < 2^127); exact fold into K2
    float mx = g;
    mx = fmaxf(mx, dppmov<0xB1>(mx));
    mx = fmaxf(mx, dppmov<0x4E>(mx));
    mx = fmaxf(mx, dppmov<0x141>(mx));
    mx = fmaxf(mx, dppmov<0x140>(mx));
    float rr = 1.0f / mx;
    K2 -= __log2f(rr);
    g *= rr;
    s0 += 16;
  }
  for (int c = 0; c < rem; ++c) {
    float pe = exp2f(raw[c]);
    g = crf_step(g, pe, E);
  }

  // ---- final logsumexp across the 16 alphas ----
  float x = g;
  x += dppmov<0xB1>(x);
  x += dppmov<0x4E>(x);
  x += dppmov<0x141>(x);
  x += dppmov<0x140>(x);
  float log_norm = LN2 * (K2 + __log2f(x));
  if (lane == 0) out_ll[b] = sc - log_norm;
}

// ---------------------------------------------------------------------------
extern "C" void kernel_launch(void* const* d_in, const int* in_sizes, int n_in,
                              void* d_out, int out_size, void* d_ws, size_t ws_size,
                              hipStream_t stream) {
  const int* text = (const int*)d_in[0];
  const int* tags = (const int*)d_in[1];
  const float* emb = (const float*)d_in[2];
  const float* W = (const float*)d_in[3];
  const float* bias = (const float*)d_in[4];
  const float* trans = (const float*)d_in[5];

  float* out = (float*)d_out;
  float* out_probs = out;                   // 64*512*16
  float* out_lens = out + BB * SS * NT;     // 64
  float* out_ll = out + BB * SS * NT + BB;  // 64

  void* args[] = {(void*)&text, (void*)&tags, (void*)&emb,   (void*)&W,
                  (void*)&bias, (void*)&trans, (void*)&out_probs,
                  (void*)&out_lens, (void*)&out_ll};
  hipLaunchCooperativeKernel((void*)fused_kernel, dim3(GRID), dim3(BLK), args,
                             0, stream);
}